// Round 4
// baseline (1569.045 us; speedup 1.0000x reference)
//
#include <hip/hip_runtime.h>

#define IN_CH 65
#define HID 64
#define BN 128      // nodes per bucket
#define NB 782      // ceil(100000 / BN)
#define CAP 8192    // pair slots per bucket; deg ~ Poisson(4096), sd 64
#define EPB 8192    // edges per scatter block
#define ASTRIDE 65  // LDS acc row stride (rotate-1 banking)

static inline size_t align16(size_t v) { return (v + 15) & ~(size_t)15; }

// ---------------------------------------------------------------------------
// prep_wt: Wt[c][j], c in [0,65), j in [0,128): j<64 -> W_rel[j][c],
// j>=64 -> W_root[j-64][c].
// ---------------------------------------------------------------------------
__global__ __launch_bounds__(128) void prep_wt(const float* __restrict__ W_rel,
                                               const float* __restrict__ W_root,
                                               float* __restrict__ Wt) {
    const int j = threadIdx.x;
    const float* W = (j < HID) ? (W_rel + j * IN_CH) : (W_root + (j - HID) * IN_CH);
    for (int c = 0; c < IN_CH; ++c)
        Wt[c * 128 + j] = W[c];
}

// ---------------------------------------------------------------------------
// k1: [64 x 65] @ [65 x 128] per block. cols<64 -> y, cols>=64 -> out(+bias).
// ---------------------------------------------------------------------------
__global__ __launch_bounds__(256) void k1(const float* __restrict__ x,
                                          const float* __restrict__ Wt,
                                          const float* __restrict__ b_rel,
                                          float* __restrict__ y,
                                          float* __restrict__ out,
                                          int nNodes) {
    __shared__ float xs[64 * IN_CH];
    __shared__ float ws[IN_CH * 128];
    const int tid = threadIdx.x;
    const int tx = tid & 15;
    const int ty = tid >> 4;
    const long nodeBase = (long)blockIdx.x * 64;
    const int nValid = min(64, nNodes - (int)nodeBase);
    const int nx = nValid * IN_CH;

    const float* xsrc = x + nodeBase * IN_CH;
    for (int i = tid; i < 64 * IN_CH; i += 256) xs[i] = (i < nx) ? xsrc[i] : 0.f;
    for (int i = tid; i < IN_CH * 128; i += 256) ws[i] = Wt[i];
    __syncthreads();

    float acc[4][8];
#pragma unroll
    for (int i = 0; i < 4; ++i)
#pragma unroll
        for (int j = 0; j < 8; ++j) acc[i][j] = 0.f;

    const int r0 = ty * 4;
    const int c0 = tx * 8;
    for (int k = 0; k < IN_CH; ++k) {
        float aa[4] = {xs[(r0 + 0) * IN_CH + k], xs[(r0 + 1) * IN_CH + k],
                       xs[(r0 + 2) * IN_CH + k], xs[(r0 + 3) * IN_CH + k]};
        float4 b0 = *(const float4*)&ws[k * 128 + c0];
        float4 b1 = *(const float4*)&ws[k * 128 + c0 + 4];
        float bb[8] = {b0.x, b0.y, b0.z, b0.w, b1.x, b1.y, b1.z, b1.w};
#pragma unroll
        for (int i = 0; i < 4; ++i)
#pragma unroll
            for (int j = 0; j < 8; ++j) acc[i][j] += aa[i] * bb[j];
    }

    if (c0 >= HID) {
        const int h0 = c0 - HID;
        float4 bb0 = *(const float4*)&b_rel[h0];
        float4 bb1 = *(const float4*)&b_rel[h0 + 4];
        float bv[8] = {bb0.x, bb0.y, bb0.z, bb0.w, bb1.x, bb1.y, bb1.z, bb1.w};
#pragma unroll
        for (int i = 0; i < 4; ++i)
#pragma unroll
            for (int j = 0; j < 8; ++j) acc[i][j] += bv[j];
    }

#pragma unroll
    for (int i = 0; i < 4; ++i) {
        const long node = nodeBase + r0 + i;
        if (node >= nNodes) break;
        float* dst = (c0 < HID) ? (y + node * HID + c0)
                                : (out + node * HID + (c0 - HID));
        *(float4*)(dst + 0) = make_float4(acc[i][0], acc[i][1], acc[i][2], acc[i][3]);
        *(float4*)(dst + 4) = make_float4(acc[i][4], acc[i][5], acc[i][6], acc[i][7]);
    }
}

// ---------------------------------------------------------------------------
// scatterB: coarse bucket partition; per-block contiguous runs (low write-amp).
// pair = (src | dstLocal<<17, bits(w)). Re-reads ei in phase 3 (L2-hot)
// instead of caching dst in a runtime-indexed per-thread array (scratch risk).
// ---------------------------------------------------------------------------
__global__ __launch_bounds__(256) void scatterB(const int* __restrict__ ei,
                                                const float* __restrict__ ew,
                                                int* __restrict__ cnt,
                                                int2* __restrict__ pairs, int E) {
    __shared__ int lhist[NB];
    __shared__ int lbase[NB];
    const int tid = threadIdx.x;
    const long e0 = (long)blockIdx.x * EPB;
    const int n = (int)min((long)EPB, (long)E - e0);

    for (int i = tid; i < NB; i += 256) lhist[i] = 0;
    __syncthreads();

    for (int i = tid; i < n; i += 256)
        atomicAdd(&lhist[ei[(long)E + e0 + i] >> 7], 1);
    __syncthreads();

    for (int i = tid; i < NB; i += 256) {
        const int c = lhist[i];
        lbase[i] = c ? atomicAdd(&cnt[i], c) : 0;
        lhist[i] = 0;  // reuse as local cursor
    }
    __syncthreads();

    for (int i = tid; i < n; i += 256) {
        const int dst = ei[(long)E + e0 + i];
        const int src = ei[e0 + i];
        const float w = ew[e0 + i];
        const int b = dst >> 7;
        const int p = lbase[b] + atomicAdd(&lhist[b], 1);
        pairs[(size_t)b * CAP + p] =
            make_int2(src | ((dst & (BN - 1)) << 17), __float_as_int(w));
    }
}

// ---------------------------------------------------------------------------
// aggregateB: one 1024-thread block per bucket. 16 threads/edge: thread r
// float4-gathers slice r of y[src] -> 4 ds_add_f32 into padded LDS acc.
// Cross-lane MLP: per wave-iter 8 independent 256B gathers (4 edges x 2 unroll)
// vs R3's 1. acc stride 65 rotates banks per row (random rows -> ~2-way, free).
// Epilogue: block owns nodes [b*128, b*128+128) exclusively -> plain +=.
// ---------------------------------------------------------------------------
__global__ __launch_bounds__(1024) void aggregateB(const int2* __restrict__ pairs,
                                                   const int* __restrict__ cnt,
                                                   const float* __restrict__ y,
                                                   float* __restrict__ out, int N) {
    __shared__ float acc[BN * ASTRIDE];  // 33280 B
    const int tid = threadIdx.x;
    const int g = tid >> 4;   // 0..63 edge slot
    const int r = tid & 15;   // float4 slice
    const int b = blockIdx.x;

    for (int i = tid; i < BN * ASTRIDE; i += 1024) acc[i] = 0.f;
    __syncthreads();

    const int m = min(cnt[b], CAP);
    const int2* pb = pairs + (size_t)b * CAP;
    const float4* yf4 = (const float4*)y;

    int k = g;
    for (; k + 64 < m; k += 128) {
        const int2 pa = pb[k];
        const int2 pc = pb[k + 64];
        const float4 va = yf4[(size_t)(pa.x & 0x1FFFF) * 16 + r];
        const float4 vc = yf4[(size_t)(pc.x & 0x1FFFF) * 16 + r];
        const float wa = __int_as_float(pa.y);
        const float wc = __int_as_float(pc.y);
        float* Aa = &acc[(pa.x >> 17) * ASTRIDE + r * 4];
        float* Ac = &acc[(pc.x >> 17) * ASTRIDE + r * 4];
        atomicAdd(Aa + 0, wa * va.x);
        atomicAdd(Aa + 1, wa * va.y);
        atomicAdd(Aa + 2, wa * va.z);
        atomicAdd(Aa + 3, wa * va.w);
        atomicAdd(Ac + 0, wc * vc.x);
        atomicAdd(Ac + 1, wc * vc.y);
        atomicAdd(Ac + 2, wc * vc.z);
        atomicAdd(Ac + 3, wc * vc.w);
    }
    if (k < m) {
        const int2 p = pb[k];
        const float4 v = yf4[(size_t)(p.x & 0x1FFFF) * 16 + r];
        const float w = __int_as_float(p.y);
        float* A = &acc[(p.x >> 17) * ASTRIDE + r * 4];
        atomicAdd(A + 0, w * v.x);
        atomicAdd(A + 1, w * v.y);
        atomicAdd(A + 2, w * v.z);
        atomicAdd(A + 3, w * v.w);
    }
    __syncthreads();

    const long nodeBase = (long)b * BN;
    for (int i = tid; i < BN * HID; i += 1024) {
        const int nloc = i >> 6;
        const int ch = i & 63;
        const long node = nodeBase + nloc;
        if (node < N) out[node * HID + ch] += acc[nloc * ASTRIDE + ch];
    }
}

// Fallback (R1 path): 16 thr/edge atomic scatter.
__global__ __launch_bounds__(256) void k2_atomic(const int* __restrict__ ei,
                                                 const float* __restrict__ ew,
                                                 const float* __restrict__ y,
                                                 float* __restrict__ out, int E) {
    const long t = (long)blockIdx.x * 256 + threadIdx.x;
    const long e = t >> 4;
    const int r = (int)(t & 15);
    if (e >= E) return;
    const int src = ei[e];
    const int dst = ei[(long)E + e];
    const float w = ew[e];
    const float4 v = ((const float4*)y)[(size_t)src * 16 + r];
    float* o = out + (size_t)dst * HID + r * 4;
    unsafeAtomicAdd(o + 0, w * v.x);
    unsafeAtomicAdd(o + 1, w * v.y);
    unsafeAtomicAdd(o + 2, w * v.z);
    unsafeAtomicAdd(o + 3, w * v.w);
}

extern "C" void kernel_launch(void* const* d_in, const int* in_sizes, int n_in,
                              void* d_out, int out_size, void* d_ws, size_t ws_size,
                              hipStream_t stream) {
    const float* x      = (const float*)d_in[0];
    const int*   ei     = (const int*)d_in[1];
    const float* ew     = (const float*)d_in[2];
    const float* W_rel  = (const float*)d_in[3];
    const float* b_rel  = (const float*)d_in[4];
    const float* W_root = (const float*)d_in[5];
    float* out = (float*)d_out;

    const int N = in_sizes[0] / IN_CH;  // 100000
    const int E = in_sizes[2];          // 3200000

    // ws layout: y | pairs | cnt | Wt
    char* base = (char*)d_ws;
    const size_t oY     = 0;
    const size_t oPairs = align16((size_t)N * HID * 4);
    const size_t oCnt   = oPairs + align16((size_t)NB * CAP * 8);
    const size_t oWt    = oCnt + align16((size_t)NB * 4);
    const size_t need   = oWt + (size_t)IN_CH * 128 * 4;

    float* y = (float*)(base + oY);

    const bool fits = (ws_size >= need) && (N <= 100096) && (N <= (1 << 17)) &&
                      ((size_t)NB * BN >= (size_t)N);

    if (fits) {
        int2* pairs = (int2*)(base + oPairs);
        int*  cnt   = (int*)(base + oCnt);
        float* Wt   = (float*)(base + oWt);

        prep_wt<<<1, 128, 0, stream>>>(W_rel, W_root, Wt);
        k1<<<(N + 63) / 64, 256, 0, stream>>>(x, Wt, b_rel, y, out, N);
        hipMemsetAsync(cnt, 0, (size_t)NB * 4, stream);
        scatterB<<<(E + EPB - 1) / EPB, 256, 0, stream>>>(ei, ew, cnt, pairs, E);
        aggregateB<<<NB, 1024, 0, stream>>>(pairs, cnt, y, out, N);
    } else {
        float* Wt = (float*)(base + align16((size_t)N * HID * 4));
        prep_wt<<<1, 128, 0, stream>>>(W_rel, W_root, Wt);
        k1<<<(N + 63) / 64, 256, 0, stream>>>(x, Wt, b_rel, y, out, N);
        const long thr2 = (long)E * 16;
        k2_atomic<<<(int)((thr2 + 255) / 256), 256, 0, stream>>>(ei, ew, y, out, E);
    }
}

// Round 5
// 353.315 us; speedup vs baseline: 4.4409x; 4.4409x over previous
//
#include <hip/hip_runtime.h>

#define IN_CH 65
#define HID 64
#define BN 128       // nodes per bucket
#define NB 782       // ceil(100000 / BN)
#define CAP 8192     // pair slots per bucket (scatter safety)
#define SCAP 4608    // LDS sorted capacity: mean 4096..4224, +6 sigma
#define EPB 8192     // edges per scatter block

static inline size_t align16(size_t v) { return (v + 15) & ~(size_t)15; }

// ---------------------------------------------------------------------------
// prep_wt: Wt[c][j], c in [0,65), j in [0,128): j<64 -> W_rel[j][c],
// j>=64 -> W_root[j-64][c].
// ---------------------------------------------------------------------------
__global__ __launch_bounds__(128) void prep_wt(const float* __restrict__ W_rel,
                                               const float* __restrict__ W_root,
                                               float* __restrict__ Wt) {
    const int j = threadIdx.x;
    const float* W = (j < HID) ? (W_rel + j * IN_CH) : (W_root + (j - HID) * IN_CH);
    for (int c = 0; c < IN_CH; ++c)
        Wt[c * 128 + j] = W[c];
}

// ---------------------------------------------------------------------------
// k1: [64 x 65] @ [65 x 128] per block. cols<64 -> y, cols>=64 -> out(+bias).
// ---------------------------------------------------------------------------
__global__ __launch_bounds__(256) void k1(const float* __restrict__ x,
                                          const float* __restrict__ Wt,
                                          const float* __restrict__ b_rel,
                                          float* __restrict__ y,
                                          float* __restrict__ out,
                                          int nNodes) {
    __shared__ float xs[64 * IN_CH];
    __shared__ float ws[IN_CH * 128];
    const int tid = threadIdx.x;
    const int tx = tid & 15;
    const int ty = tid >> 4;
    const long nodeBase = (long)blockIdx.x * 64;
    const int nValid = min(64, nNodes - (int)nodeBase);
    const int nx = nValid * IN_CH;

    const float* xsrc = x + nodeBase * IN_CH;
    for (int i = tid; i < 64 * IN_CH; i += 256) xs[i] = (i < nx) ? xsrc[i] : 0.f;
    for (int i = tid; i < IN_CH * 128; i += 256) ws[i] = Wt[i];
    __syncthreads();

    float acc[4][8];
#pragma unroll
    for (int i = 0; i < 4; ++i)
#pragma unroll
        for (int j = 0; j < 8; ++j) acc[i][j] = 0.f;

    const int r0 = ty * 4;
    const int c0 = tx * 8;
    for (int k = 0; k < IN_CH; ++k) {
        float aa[4] = {xs[(r0 + 0) * IN_CH + k], xs[(r0 + 1) * IN_CH + k],
                       xs[(r0 + 2) * IN_CH + k], xs[(r0 + 3) * IN_CH + k]};
        float4 b0 = *(const float4*)&ws[k * 128 + c0];
        float4 b1 = *(const float4*)&ws[k * 128 + c0 + 4];
        float bb[8] = {b0.x, b0.y, b0.z, b0.w, b1.x, b1.y, b1.z, b1.w};
#pragma unroll
        for (int i = 0; i < 4; ++i)
#pragma unroll
            for (int j = 0; j < 8; ++j) acc[i][j] += aa[i] * bb[j];
    }

    if (c0 >= HID) {
        const int h0 = c0 - HID;
        float4 bb0 = *(const float4*)&b_rel[h0];
        float4 bb1 = *(const float4*)&b_rel[h0 + 4];
        float bv[8] = {bb0.x, bb0.y, bb0.z, bb0.w, bb1.x, bb1.y, bb1.z, bb1.w};
#pragma unroll
        for (int i = 0; i < 4; ++i)
#pragma unroll
            for (int j = 0; j < 8; ++j) acc[i][j] += bv[j];
    }

#pragma unroll
    for (int i = 0; i < 4; ++i) {
        const long node = nodeBase + r0 + i;
        if (node >= nNodes) break;
        float* dst = (c0 < HID) ? (y + node * HID + c0)
                                : (out + node * HID + (c0 - HID));
        *(float4*)(dst + 0) = make_float4(acc[i][0], acc[i][1], acc[i][2], acc[i][3]);
        *(float4*)(dst + 4) = make_float4(acc[i][4], acc[i][5], acc[i][6], acc[i][7]);
    }
}

// ---------------------------------------------------------------------------
// scatterB: coarse bucket partition; per-block contiguous runs (low write-amp).
// pair = (src | dstLocal<<17, bits(w)).
// ---------------------------------------------------------------------------
__global__ __launch_bounds__(256) void scatterB(const int* __restrict__ ei,
                                                const float* __restrict__ ew,
                                                int* __restrict__ cnt,
                                                int2* __restrict__ pairs, int E) {
    __shared__ int lhist[NB];
    __shared__ int lbase[NB];
    const int tid = threadIdx.x;
    const long e0 = (long)blockIdx.x * EPB;
    const int n = (int)min((long)EPB, (long)E - e0);

    for (int i = tid; i < NB; i += 256) lhist[i] = 0;
    __syncthreads();

    for (int i = tid; i < n; i += 256)
        atomicAdd(&lhist[ei[(long)E + e0 + i] >> 7], 1);
    __syncthreads();

    for (int i = tid; i < NB; i += 256) {
        const int c = lhist[i];
        lbase[i] = c ? atomicAdd(&cnt[i], c) : 0;
        lhist[i] = 0;  // reuse as local cursor
    }
    __syncthreads();

    for (int i = tid; i < n; i += 256) {
        const int dst = ei[(long)E + e0 + i];
        const int src = ei[e0 + i];
        const float w = ew[e0 + i];
        const int b = dst >> 7;
        const int p = lbase[b] + atomicAdd(&lhist[b], 1);
        if (p < CAP)
            pairs[(size_t)b * CAP + p] =
                make_int2(src | ((dst & (BN - 1)) << 17), __float_as_int(w));
    }
}

// ---------------------------------------------------------------------------
// aggregateS: one 512-thread block per bucket.
// Phase A: LDS counting sort of the bucket's pairs into per-node segments
//          (int cursor atomics only — no float atomics anywhere).
// Phase B: wave w owns nodes w, w+8, ... exclusively; per edge: broadcast
//          ds_read of pair, coalesced 256B gather of y[src], FMA into a
//          REGISTER accumulator. 4-edge unroll -> 4 gathers in flight/wave.
// ---------------------------------------------------------------------------
__global__ __launch_bounds__(512) void aggregateS(const int2* __restrict__ pairs,
                                                  const int* __restrict__ cnt,
                                                  const float* __restrict__ y,
                                                  float* __restrict__ out, int N) {
    __shared__ int2 sorted[SCAP];   // 36 KB
    __shared__ int sH[128];         // hist -> inclusive scan
    __shared__ int soff[129];       // exclusive offsets
    __shared__ int scur[128];       // scatter cursors
    const int tid = threadIdx.x;
    const int lane = tid & 63;
    const int wv = tid >> 6;  // 0..7
    const int b = blockIdx.x;

    if (tid < 128) { sH[tid] = 0; scur[tid] = 0; }
    __syncthreads();

    const int m = min(cnt[b], CAP);
    const int2* pb = pairs + (size_t)b * CAP;

    // Pass 1: histogram of dstLocal
    for (int i = tid; i < m; i += 512)
        atomicAdd(&sH[pb[i].x >> 17], 1);
    __syncthreads();

    // Inclusive scan over 128 (Hillis-Steele, read-then-write with barriers)
    for (int off = 1; off < 128; off <<= 1) {
        int v = 0;
        if (tid < 128) {
            v = sH[tid];
            if (tid >= off) v += sH[tid - off];
        }
        __syncthreads();
        if (tid < 128) sH[tid] = v;
        __syncthreads();
    }
    if (tid < 128) soff[tid + 1] = sH[tid];
    if (tid == 0) soff[0] = 0;
    __syncthreads();

    // Pass 2: scatter into per-node segments (drop dstLocal; position encodes it)
    for (int i = tid; i < m; i += 512) {
        const int2 p = pb[i];
        const int d = p.x >> 17;
        const int slot = soff[d] + atomicAdd(&scur[d], 1);
        if (slot < SCAP) sorted[slot] = make_int2(p.x & 0x1FFFF, p.y);
    }
    __syncthreads();

    // Phase B: register-accumulated per-node reduction
    const long nodeBase = (long)b * BN;
    for (int nl = wv; nl < BN; nl += 8) {
        const long node = nodeBase + nl;
        if (node >= N) break;
        const int kbeg = min(soff[nl], SCAP);
        const int kend = min(soff[nl + 1], SCAP);
        float acc = 0.f;
        int k = kbeg;
        for (; k + 4 <= kend; k += 4) {
            const int2 p0 = sorted[k], p1 = sorted[k + 1];
            const int2 p2 = sorted[k + 2], p3 = sorted[k + 3];
            const float v0 = y[(size_t)p0.x * HID + lane];
            const float v1 = y[(size_t)p1.x * HID + lane];
            const float v2 = y[(size_t)p2.x * HID + lane];
            const float v3 = y[(size_t)p3.x * HID + lane];
            acc += __int_as_float(p0.y) * v0;
            acc += __int_as_float(p1.y) * v1;
            acc += __int_as_float(p2.y) * v2;
            acc += __int_as_float(p3.y) * v3;
        }
        for (; k < kend; ++k) {
            const int2 p = sorted[k];
            acc += __int_as_float(p.y) * y[(size_t)p.x * HID + lane];
        }
        out[node * HID + lane] += acc;  // wave owns this row exclusively
    }
}

// Fallback (R1 path): 16 thr/edge atomic scatter.
__global__ __launch_bounds__(256) void k2_atomic(const int* __restrict__ ei,
                                                 const float* __restrict__ ew,
                                                 const float* __restrict__ y,
                                                 float* __restrict__ out, int E) {
    const long t = (long)blockIdx.x * 256 + threadIdx.x;
    const long e = t >> 4;
    const int r = (int)(t & 15);
    if (e >= E) return;
    const int src = ei[e];
    const int dst = ei[(long)E + e];
    const float w = ew[e];
    const float4 v = ((const float4*)y)[(size_t)src * 16 + r];
    float* o = out + (size_t)dst * HID + r * 4;
    unsafeAtomicAdd(o + 0, w * v.x);
    unsafeAtomicAdd(o + 1, w * v.y);
    unsafeAtomicAdd(o + 2, w * v.z);
    unsafeAtomicAdd(o + 3, w * v.w);
}

extern "C" void kernel_launch(void* const* d_in, const int* in_sizes, int n_in,
                              void* d_out, int out_size, void* d_ws, size_t ws_size,
                              hipStream_t stream) {
    const float* x      = (const float*)d_in[0];
    const int*   ei     = (const int*)d_in[1];
    const float* ew     = (const float*)d_in[2];
    const float* W_rel  = (const float*)d_in[3];
    const float* b_rel  = (const float*)d_in[4];
    const float* W_root = (const float*)d_in[5];
    float* out = (float*)d_out;

    const int N = in_sizes[0] / IN_CH;  // 100000
    const int E = in_sizes[2];          // 3200000

    // ws layout: y | pairs | cnt | Wt
    char* base = (char*)d_ws;
    const size_t oY     = 0;
    const size_t oPairs = align16((size_t)N * HID * 4);
    const size_t oCnt   = oPairs + align16((size_t)NB * CAP * 8);
    const size_t oWt    = oCnt + align16((size_t)NB * 4);
    const size_t need   = oWt + (size_t)IN_CH * 128 * 4;

    float* y = (float*)(base + oY);

    // bucket path needs: ws room, src < 2^17, geometry, and mean bucket
    // load E/N*128 comfortably under SCAP (sorted LDS capacity)
    const bool fits = (ws_size >= need) && (N <= 100096) && (N <= (1 << 17)) &&
                      ((size_t)NB * BN >= (size_t)N) && ((long)E <= (long)N * 33);

    if (fits) {
        int2* pairs = (int2*)(base + oPairs);
        int*  cnt   = (int*)(base + oCnt);
        float* Wt   = (float*)(base + oWt);

        prep_wt<<<1, 128, 0, stream>>>(W_rel, W_root, Wt);
        k1<<<(N + 63) / 64, 256, 0, stream>>>(x, Wt, b_rel, y, out, N);
        hipMemsetAsync(cnt, 0, (size_t)NB * 4, stream);
        scatterB<<<(E + EPB - 1) / EPB, 256, 0, stream>>>(ei, ew, cnt, pairs, E);
        aggregateS<<<NB, 512, 0, stream>>>(pairs, cnt, y, out, N);
    } else {
        float* Wt = (float*)(base + align16((size_t)N * HID * 4));
        prep_wt<<<1, 128, 0, stream>>>(W_rel, W_root, Wt);
        k1<<<(N + 63) / 64, 256, 0, stream>>>(x, Wt, b_rel, y, out, N);
        const long thr2 = (long)E * 16;
        k2_atomic<<<(int)((thr2 + 255) / 256), 256, 0, stream>>>(ei, ew, y, out, E);
    }
}

// Round 6
// 315.271 us; speedup vs baseline: 4.9768x; 1.1207x over previous
//
#include <hip/hip_runtime.h>

#define IN_CH 65
#define HID 64
#define BN 64        // nodes per bucket
#define NB 1563      // ceil(100000 / BN)
#define CAP 2560     // pair slots per bucket (mean 2048, +11 sigma)
#define SCAP 2432    // LDS sorted capacity (mean 2048, +8.5 sigma)
#define EPB 8192     // edges per scatter block

static inline size_t align16(size_t v) { return (v + 15) & ~(size_t)15; }

__device__ inline ushort f2bf(float f) {
    uint u = __float_as_uint(f);
    return (ushort)((u + 0x7FFF + ((u >> 16) & 1)) >> 16);  // RNE
}
__device__ inline float bf2f(ushort h) { return __uint_as_float((uint)h << 16); }

// ---------------------------------------------------------------------------
// k1: per 64-node tile: y16 = bf16(x @ W_rel.T), out = x @ W_root.T + b_rel.
// Wt built in-kernel from raw W (33 KB, L1/L2-hot) — prep_wt kernel removed.
// Also zeroes cnt[blockIdx.x] (grid == NB) so the memset dispatch is removed.
// ---------------------------------------------------------------------------
__global__ __launch_bounds__(256) void k1(const float* __restrict__ x,
                                          const float* __restrict__ W_rel,
                                          const float* __restrict__ b_rel,
                                          const float* __restrict__ W_root,
                                          ushort* __restrict__ y16,
                                          float* __restrict__ out,
                                          int* __restrict__ cnt, int nBuckets,
                                          int nNodes) {
    __shared__ float xs[64 * IN_CH];   // 16.6 KB
    __shared__ float ws[IN_CH * 128];  // 33.3 KB
    const int tid = threadIdx.x;
    const int tx = tid & 15;
    const int ty = tid >> 4;
    const long nodeBase = (long)blockIdx.x * 64;
    const int nValid = min(64, nNodes - (int)nodeBase);
    const int nx = nValid * IN_CH;

    if (cnt && tid == 0 && blockIdx.x < (unsigned)nBuckets) cnt[blockIdx.x] = 0;

    // ws[c*128+j] = (j<64 ? W_rel[j][c] : W_root[j-64][c]); source is 33 KB,
    // L1-resident after first iteration per CU.
    for (int i = tid; i < IN_CH * 128; i += 256) {
        const int c = i >> 7, j = i & 127;
        ws[i] = (j < HID) ? W_rel[j * IN_CH + c] : W_root[(j - HID) * IN_CH + c];
    }
    const float* xsrc = x + nodeBase * IN_CH;
    for (int i = tid; i < 64 * IN_CH; i += 256) xs[i] = (i < nx) ? xsrc[i] : 0.f;
    __syncthreads();

    float acc[4][8];
#pragma unroll
    for (int i = 0; i < 4; ++i)
#pragma unroll
        for (int j = 0; j < 8; ++j) acc[i][j] = 0.f;

    const int r0 = ty * 4;
    const int c0 = tx * 8;
    for (int k = 0; k < IN_CH; ++k) {
        float aa[4] = {xs[(r0 + 0) * IN_CH + k], xs[(r0 + 1) * IN_CH + k],
                       xs[(r0 + 2) * IN_CH + k], xs[(r0 + 3) * IN_CH + k]};
        float4 b0 = *(const float4*)&ws[k * 128 + c0];
        float4 b1 = *(const float4*)&ws[k * 128 + c0 + 4];
        float bb[8] = {b0.x, b0.y, b0.z, b0.w, b1.x, b1.y, b1.z, b1.w};
#pragma unroll
        for (int i = 0; i < 4; ++i)
#pragma unroll
            for (int j = 0; j < 8; ++j) acc[i][j] += aa[i] * bb[j];
    }

    if (c0 >= HID) {
        const int h0 = c0 - HID;
        float4 bb0 = *(const float4*)&b_rel[h0];
        float4 bb1 = *(const float4*)&b_rel[h0 + 4];
        float bv[8] = {bb0.x, bb0.y, bb0.z, bb0.w, bb1.x, bb1.y, bb1.z, bb1.w};
#pragma unroll
        for (int i = 0; i < 4; ++i)
#pragma unroll
            for (int j = 0; j < 8; ++j) acc[i][j] += bv[j];
    }

#pragma unroll
    for (int i = 0; i < 4; ++i) {
        const long node = nodeBase + r0 + i;
        if (node >= nNodes) break;
        if (c0 < HID) {  // y half: pack 8 bf16 = 16 B store
            uint4 pk;
            pk.x = (uint)f2bf(acc[i][0]) | ((uint)f2bf(acc[i][1]) << 16);
            pk.y = (uint)f2bf(acc[i][2]) | ((uint)f2bf(acc[i][3]) << 16);
            pk.z = (uint)f2bf(acc[i][4]) | ((uint)f2bf(acc[i][5]) << 16);
            pk.w = (uint)f2bf(acc[i][6]) | ((uint)f2bf(acc[i][7]) << 16);
            *(uint4*)&y16[node * HID + c0] = pk;  // node*128B + c0*2B, 16B-aligned
        } else {
            float* dst = out + node * HID + (c0 - HID);
            *(float4*)(dst + 0) = make_float4(acc[i][0], acc[i][1], acc[i][2], acc[i][3]);
            *(float4*)(dst + 4) = make_float4(acc[i][4], acc[i][5], acc[i][6], acc[i][7]);
        }
    }
}

// ---------------------------------------------------------------------------
// scatterB: coarse bucket partition (bucket = dst>>6); per-block contiguous
// runs keep write amplification low. pair = (src | dstLocal<<17, bits(w)).
// ---------------------------------------------------------------------------
__global__ __launch_bounds__(256) void scatterB(const int* __restrict__ ei,
                                                const float* __restrict__ ew,
                                                int* __restrict__ cnt,
                                                int2* __restrict__ pairs, int E) {
    __shared__ int lhist[NB];  // 6.2 KB
    __shared__ int lbase[NB];
    const int tid = threadIdx.x;
    const long e0 = (long)blockIdx.x * EPB;
    const int n = (int)min((long)EPB, (long)E - e0);

    for (int i = tid; i < NB; i += 256) lhist[i] = 0;
    __syncthreads();

    for (int i = tid; i < n; i += 256)
        atomicAdd(&lhist[ei[(long)E + e0 + i] >> 6], 1);
    __syncthreads();

    for (int i = tid; i < NB; i += 256) {
        const int c = lhist[i];
        lbase[i] = c ? atomicAdd(&cnt[i], c) : 0;
        lhist[i] = 0;  // reuse as local cursor
    }
    __syncthreads();

    for (int i = tid; i < n; i += 256) {
        const int dst = ei[(long)E + e0 + i];
        const int src = ei[e0 + i];
        const float w = ew[e0 + i];
        const int b = dst >> 6;
        const int p = lbase[b] + atomicAdd(&lhist[b], 1);
        if (p < CAP)
            pairs[(size_t)b * CAP + p] =
                make_int2(src | ((dst & (BN - 1)) << 17), __float_as_int(w));
    }
}

// ---------------------------------------------------------------------------
// aggregateS16: one 512-thread block per 64-node bucket.
// Phase A: LDS counting sort into per-node segments (int atomics only).
// Phase B: wave w owns nodes w, w+8,...; per edge: broadcast ds_read of pair,
//          ONE 128B coalesced bf16 gather of y16[src], FMA into registers.
// ---------------------------------------------------------------------------
__global__ __launch_bounds__(512) void aggregateS16(const int2* __restrict__ pairs,
                                                    const int* __restrict__ cnt,
                                                    const ushort* __restrict__ y16,
                                                    float* __restrict__ out, int N) {
    __shared__ int2 sorted[SCAP];  // 19.5 KB
    __shared__ int sH[BN];
    __shared__ int soff[BN + 1];
    __shared__ int scur[BN];
    const int tid = threadIdx.x;
    const int lane = tid & 63;
    const int wv = tid >> 6;  // 0..7
    const int b = blockIdx.x;

    if (tid < BN) { sH[tid] = 0; scur[tid] = 0; }
    __syncthreads();

    const int m = min(cnt[b], CAP);
    const int2* pb = pairs + (size_t)b * CAP;

    for (int i = tid; i < m; i += 512)
        atomicAdd(&sH[pb[i].x >> 17], 1);
    __syncthreads();

    // inclusive scan over 64
    for (int off = 1; off < BN; off <<= 1) {
        int v = 0;
        if (tid < BN) {
            v = sH[tid];
            if (tid >= off) v += sH[tid - off];
        }
        __syncthreads();
        if (tid < BN) sH[tid] = v;
        __syncthreads();
    }
    if (tid < BN) soff[tid + 1] = sH[tid];
    if (tid == 0) soff[0] = 0;
    __syncthreads();

    for (int i = tid; i < m; i += 512) {
        const int2 p = pb[i];
        const int d = p.x >> 17;
        const int slot = soff[d] + atomicAdd(&scur[d], 1);
        if (slot < SCAP) sorted[slot] = make_int2(p.x & 0x1FFFF, p.y);
    }
    __syncthreads();

    const long nodeBase = (long)b * BN;
    for (int nl = wv; nl < BN; nl += 8) {
        const long node = nodeBase + nl;
        if (node >= N) break;
        const int kbeg = min(soff[nl], SCAP);
        const int kend = min(soff[nl + 1], SCAP);
        float acc = 0.f;
        int k = kbeg;
        for (; k + 4 <= kend; k += 4) {
            const int2 p0 = sorted[k], p1 = sorted[k + 1];
            const int2 p2 = sorted[k + 2], p3 = sorted[k + 3];
            const float v0 = bf2f(y16[(size_t)p0.x * HID + lane]);
            const float v1 = bf2f(y16[(size_t)p1.x * HID + lane]);
            const float v2 = bf2f(y16[(size_t)p2.x * HID + lane]);
            const float v3 = bf2f(y16[(size_t)p3.x * HID + lane]);
            acc += __int_as_float(p0.y) * v0;
            acc += __int_as_float(p1.y) * v1;
            acc += __int_as_float(p2.y) * v2;
            acc += __int_as_float(p3.y) * v3;
        }
        for (; k < kend; ++k) {
            const int2 p = sorted[k];
            acc += __int_as_float(p.y) * bf2f(y16[(size_t)p.x * HID + lane]);
        }
        out[node * HID + lane] += acc;  // wave owns this row exclusively
    }
}

// Fallback: 16 thr/edge atomic scatter from bf16 y.
__global__ __launch_bounds__(256) void k2_atomic16(const int* __restrict__ ei,
                                                   const float* __restrict__ ew,
                                                   const ushort* __restrict__ y16,
                                                   float* __restrict__ out, int E) {
    const long t = (long)blockIdx.x * 256 + threadIdx.x;
    const long e = t >> 4;
    const int r = (int)(t & 15);
    if (e >= E) return;
    const int src = ei[e];
    const int dst = ei[(long)E + e];
    const float w = ew[e];
    const uint2 q = ((const uint2*)y16)[(size_t)src * 16 + r];
    float* o = out + (size_t)dst * HID + r * 4;
    unsafeAtomicAdd(o + 0, w * __uint_as_float(q.x << 16));
    unsafeAtomicAdd(o + 1, w * __uint_as_float(q.x & 0xFFFF0000u));
    unsafeAtomicAdd(o + 2, w * __uint_as_float(q.y << 16));
    unsafeAtomicAdd(o + 3, w * __uint_as_float(q.y & 0xFFFF0000u));
}

extern "C" void kernel_launch(void* const* d_in, const int* in_sizes, int n_in,
                              void* d_out, int out_size, void* d_ws, size_t ws_size,
                              hipStream_t stream) {
    const float* x      = (const float*)d_in[0];
    const int*   ei     = (const int*)d_in[1];
    const float* ew     = (const float*)d_in[2];
    const float* W_rel  = (const float*)d_in[3];
    const float* b_rel  = (const float*)d_in[4];
    const float* W_root = (const float*)d_in[5];
    float* out = (float*)d_out;

    const int N = in_sizes[0] / IN_CH;  // 100000
    const int E = in_sizes[2];          // 3200000

    // ws layout: y16 | pairs | cnt
    char* base = (char*)d_ws;
    const size_t oY     = 0;
    const size_t oPairs = align16((size_t)N * HID * 2);
    const size_t oCnt   = oPairs + align16((size_t)NB * CAP * 8);
    const size_t need   = oCnt + (size_t)NB * 4;

    ushort* y16 = (ushort*)(base + oY);
    const int nb1 = (N + 63) / 64;

    // bucket path: ws room, src < 2^17, geometry covers N, mean bucket load
    // (E/N)*64 comfortably under SCAP
    const bool fits = (ws_size >= need) && (N <= (1 << 17)) &&
                      ((size_t)NB * BN >= (size_t)N) && ((long)E <= (long)N * 33) &&
                      (nb1 >= NB);

    if (fits) {
        int2* pairs = (int2*)(base + oPairs);
        int*  cnt   = (int*)(base + oCnt);

        k1<<<nb1, 256, 0, stream>>>(x, W_rel, b_rel, W_root, y16, out, cnt, NB, N);
        scatterB<<<(E + EPB - 1) / EPB, 256, 0, stream>>>(ei, ew, cnt, pairs, E);
        aggregateS16<<<NB, 512, 0, stream>>>(pairs, cnt, y16, out, N);
    } else {
        k1<<<nb1, 256, 0, stream>>>(x, W_rel, b_rel, W_root, y16, out,
                                    (int*)nullptr, 0, N);
        const long thr2 = (long)E * 16;
        k2_atomic16<<<(int)((thr2 + 255) / 256), 256, 0, stream>>>(ei, ew, y16, out, E);
    }
}

// Round 7
// 267.143 us; speedup vs baseline: 5.8734x; 1.1802x over previous
//
#include <hip/hip_runtime.h>

#define IN_CH 65
#define HID 64
#define BN 64        // nodes per bucket
#define NB 1563      // ceil(100000 / BN)
#define CAP 2560     // pair slots per bucket (mean 2048, +11 sigma)
#define SCAP 2432    // LDS sorted capacity (mean 2048, +8.5 sigma)
#define EPB 8192     // edges per scatter block
#define TPS 1024     // scatter threads per block
#define EPT (EPB / TPS)  // 8 edges per thread

static inline size_t align16(size_t v) { return (v + 15) & ~(size_t)15; }

__device__ inline ushort f2bf(float f) {
    uint u = __float_as_uint(f);
    return (ushort)((u + 0x7FFF + ((u >> 16) & 1)) >> 16);  // RNE
}
__device__ inline float bf2f(ushort h) { return __uint_as_float((uint)h << 16); }

// ---------------------------------------------------------------------------
// k1: per 64-node tile: y16 = bf16(x @ W_rel.T), out = x @ W_root.T + b_rel.
// Builds Wt in LDS from raw W (33 KB, L1/L2-hot); zeroes cnt (grid >= NB).
// ---------------------------------------------------------------------------
__global__ __launch_bounds__(256) void k1(const float* __restrict__ x,
                                          const float* __restrict__ W_rel,
                                          const float* __restrict__ b_rel,
                                          const float* __restrict__ W_root,
                                          ushort* __restrict__ y16,
                                          float* __restrict__ out,
                                          int* __restrict__ cnt, int nBuckets,
                                          int nNodes) {
    __shared__ float xs[64 * IN_CH];   // 16.6 KB
    __shared__ float ws[IN_CH * 128];  // 33.3 KB
    const int tid = threadIdx.x;
    const int tx = tid & 15;
    const int ty = tid >> 4;
    const long nodeBase = (long)blockIdx.x * 64;
    const int nValid = min(64, nNodes - (int)nodeBase);
    const int nx = nValid * IN_CH;

    if (cnt && tid == 0 && blockIdx.x < (unsigned)nBuckets) cnt[blockIdx.x] = 0;

    for (int i = tid; i < IN_CH * 128; i += 256) {
        const int c = i >> 7, j = i & 127;
        ws[i] = (j < HID) ? W_rel[j * IN_CH + c] : W_root[(j - HID) * IN_CH + c];
    }
    const float* xsrc = x + nodeBase * IN_CH;
    for (int i = tid; i < 64 * IN_CH; i += 256) xs[i] = (i < nx) ? xsrc[i] : 0.f;
    __syncthreads();

    float acc[4][8];
#pragma unroll
    for (int i = 0; i < 4; ++i)
#pragma unroll
        for (int j = 0; j < 8; ++j) acc[i][j] = 0.f;

    const int r0 = ty * 4;
    const int c0 = tx * 8;
    for (int k = 0; k < IN_CH; ++k) {
        float aa[4] = {xs[(r0 + 0) * IN_CH + k], xs[(r0 + 1) * IN_CH + k],
                       xs[(r0 + 2) * IN_CH + k], xs[(r0 + 3) * IN_CH + k]};
        float4 b0 = *(const float4*)&ws[k * 128 + c0];
        float4 b1 = *(const float4*)&ws[k * 128 + c0 + 4];
        float bb[8] = {b0.x, b0.y, b0.z, b0.w, b1.x, b1.y, b1.z, b1.w};
#pragma unroll
        for (int i = 0; i < 4; ++i)
#pragma unroll
            for (int j = 0; j < 8; ++j) acc[i][j] += aa[i] * bb[j];
    }

    if (c0 >= HID) {
        const int h0 = c0 - HID;
        float4 bb0 = *(const float4*)&b_rel[h0];
        float4 bb1 = *(const float4*)&b_rel[h0 + 4];
        float bv[8] = {bb0.x, bb0.y, bb0.z, bb0.w, bb1.x, bb1.y, bb1.z, bb1.w};
#pragma unroll
        for (int i = 0; i < 4; ++i)
#pragma unroll
            for (int j = 0; j < 8; ++j) acc[i][j] += bv[j];
    }

#pragma unroll
    for (int i = 0; i < 4; ++i) {
        const long node = nodeBase + r0 + i;
        if (node >= nNodes) break;
        if (c0 < HID) {
            uint4 pk;
            pk.x = (uint)f2bf(acc[i][0]) | ((uint)f2bf(acc[i][1]) << 16);
            pk.y = (uint)f2bf(acc[i][2]) | ((uint)f2bf(acc[i][3]) << 16);
            pk.z = (uint)f2bf(acc[i][4]) | ((uint)f2bf(acc[i][5]) << 16);
            pk.w = (uint)f2bf(acc[i][6]) | ((uint)f2bf(acc[i][7]) << 16);
            *(uint4*)&y16[node * HID + c0] = pk;
        } else {
            float* dst = out + node * HID + (c0 - HID);
            *(float4*)(dst + 0) = make_float4(acc[i][0], acc[i][1], acc[i][2], acc[i][3]);
            *(float4*)(dst + 4) = make_float4(acc[i][4], acc[i][5], acc[i][6], acc[i][7]);
        }
    }
}

// ---------------------------------------------------------------------------
// scatterB: 1024-thread blocks, 8 edges/thread register-cached in phase 1
// (constant-indexed after full unroll -> VGPRs, no scratch). 16 waves/block,
// ~32 waves/CU: hides the LDS-atomic-return + scattered-write latency chain.
// pair = (src | dstLocal<<17, bits(w)); bucket = dst>>6.
// ---------------------------------------------------------------------------
__global__ __launch_bounds__(TPS) void scatterB(const int* __restrict__ ei,
                                                const float* __restrict__ ew,
                                                int* __restrict__ cnt,
                                                int2* __restrict__ pairs, int E) {
    __shared__ int lhist[NB];  // 6.2 KB
    __shared__ int lbase[NB];  // 6.2 KB
    const int tid = threadIdx.x;
    const long e0 = (long)blockIdx.x * EPB;
    const int n = (int)min((long)EPB, (long)E - e0);

    for (int i = tid; i < NB; i += TPS) lhist[i] = 0;
    __syncthreads();

    int dstv[EPT], srcv[EPT];
    float wv[EPT];
#pragma unroll
    for (int k = 0; k < EPT; ++k) {
        const int i = tid + k * TPS;
        const bool valid = i < n;
        dstv[k] = valid ? ei[(long)E + e0 + i] : 0;
        srcv[k] = valid ? ei[e0 + i] : 0;
        wv[k]   = valid ? ew[e0 + i] : 0.f;
        if (valid) atomicAdd(&lhist[dstv[k] >> 6], 1);
    }
    __syncthreads();

    for (int i = tid; i < NB; i += TPS) {
        const int c = lhist[i];
        lbase[i] = c ? atomicAdd(&cnt[i], c) : 0;
        lhist[i] = 0;  // reuse as local cursor
    }
    __syncthreads();

#pragma unroll
    for (int k = 0; k < EPT; ++k) {
        const int i = tid + k * TPS;
        if (i < n) {
            const int b = dstv[k] >> 6;
            const int p = lbase[b] + atomicAdd(&lhist[b], 1);
            if (p < CAP)
                pairs[(size_t)b * CAP + p] =
                    make_int2(srcv[k] | ((dstv[k] & (BN - 1)) << 17),
                              __float_as_int(wv[k]));
        }
    }
}

// ---------------------------------------------------------------------------
// aggregateS16: one 512-thread block per 64-node bucket.
// Phase A: LDS counting sort into per-node segments (int atomics only).
// Phase B: wave w owns nodes w, w+8,...; per edge one 128B bf16 gather + FMA
//          into registers. No float atomics anywhere.
// ---------------------------------------------------------------------------
__global__ __launch_bounds__(512) void aggregateS16(const int2* __restrict__ pairs,
                                                    const int* __restrict__ cnt,
                                                    const ushort* __restrict__ y16,
                                                    float* __restrict__ out, int N) {
    __shared__ int2 sorted[SCAP];  // 19.5 KB
    __shared__ int sH[BN];
    __shared__ int soff[BN + 1];
    __shared__ int scur[BN];
    const int tid = threadIdx.x;
    const int lane = tid & 63;
    const int wv = tid >> 6;  // 0..7
    const int b = blockIdx.x;

    if (tid < BN) { sH[tid] = 0; scur[tid] = 0; }
    __syncthreads();

    const int m = min(cnt[b], CAP);
    const int2* pb = pairs + (size_t)b * CAP;

    for (int i = tid; i < m; i += 512)
        atomicAdd(&sH[pb[i].x >> 17], 1);
    __syncthreads();

    for (int off = 1; off < BN; off <<= 1) {
        int v = 0;
        if (tid < BN) {
            v = sH[tid];
            if (tid >= off) v += sH[tid - off];
        }
        __syncthreads();
        if (tid < BN) sH[tid] = v;
        __syncthreads();
    }
    if (tid < BN) soff[tid + 1] = sH[tid];
    if (tid == 0) soff[0] = 0;
    __syncthreads();

    for (int i = tid; i < m; i += 512) {
        const int2 p = pb[i];
        const int d = p.x >> 17;
        const int slot = soff[d] + atomicAdd(&scur[d], 1);
        if (slot < SCAP) sorted[slot] = make_int2(p.x & 0x1FFFF, p.y);
    }
    __syncthreads();

    const long nodeBase = (long)b * BN;
    for (int nl = wv; nl < BN; nl += 8) {
        const long node = nodeBase + nl;
        if (node >= N) break;
        const int kbeg = min(soff[nl], SCAP);
        const int kend = min(soff[nl + 1], SCAP);
        float acc = 0.f;
        int k = kbeg;
        for (; k + 4 <= kend; k += 4) {
            const int2 p0 = sorted[k], p1 = sorted[k + 1];
            const int2 p2 = sorted[k + 2], p3 = sorted[k + 3];
            const float v0 = bf2f(y16[(size_t)p0.x * HID + lane]);
            const float v1 = bf2f(y16[(size_t)p1.x * HID + lane]);
            const float v2 = bf2f(y16[(size_t)p2.x * HID + lane]);
            const float v3 = bf2f(y16[(size_t)p3.x * HID + lane]);
            acc += __int_as_float(p0.y) * v0;
            acc += __int_as_float(p1.y) * v1;
            acc += __int_as_float(p2.y) * v2;
            acc += __int_as_float(p3.y) * v3;
        }
        for (; k < kend; ++k) {
            const int2 p = sorted[k];
            acc += __int_as_float(p.y) * bf2f(y16[(size_t)p.x * HID + lane]);
        }
        out[node * HID + lane] += acc;  // wave owns this row exclusively
    }
}

// Fallback: 16 thr/edge atomic scatter from bf16 y.
__global__ __launch_bounds__(256) void k2_atomic16(const int* __restrict__ ei,
                                                   const float* __restrict__ ew,
                                                   const ushort* __restrict__ y16,
                                                   float* __restrict__ out, int E) {
    const long t = (long)blockIdx.x * 256 + threadIdx.x;
    const long e = t >> 4;
    const int r = (int)(t & 15);
    if (e >= E) return;
    const int src = ei[e];
    const int dst = ei[(long)E + e];
    const float w = ew[e];
    const uint2 q = ((const uint2*)y16)[(size_t)src * 16 + r];
    float* o = out + (size_t)dst * HID + r * 4;
    unsafeAtomicAdd(o + 0, w * __uint_as_float(q.x << 16));
    unsafeAtomicAdd(o + 1, w * __uint_as_float(q.x & 0xFFFF0000u));
    unsafeAtomicAdd(o + 2, w * __uint_as_float(q.y << 16));
    unsafeAtomicAdd(o + 3, w * __uint_as_float(q.y & 0xFFFF0000u));
}

extern "C" void kernel_launch(void* const* d_in, const int* in_sizes, int n_in,
                              void* d_out, int out_size, void* d_ws, size_t ws_size,
                              hipStream_t stream) {
    const float* x      = (const float*)d_in[0];
    const int*   ei     = (const int*)d_in[1];
    const float* ew     = (const float*)d_in[2];
    const float* W_rel  = (const float*)d_in[3];
    const float* b_rel  = (const float*)d_in[4];
    const float* W_root = (const float*)d_in[5];
    float* out = (float*)d_out;

    const int N = in_sizes[0] / IN_CH;  // 100000
    const int E = in_sizes[2];          // 3200000

    // ws layout: y16 | pairs | cnt
    char* base = (char*)d_ws;
    const size_t oY     = 0;
    const size_t oPairs = align16((size_t)N * HID * 2);
    const size_t oCnt   = oPairs + align16((size_t)NB * CAP * 8);
    const size_t need   = oCnt + (size_t)NB * 4;

    ushort* y16 = (ushort*)(base + oY);
    const int nb1 = (N + 63) / 64;

    const bool fits = (ws_size >= need) && (N <= (1 << 17)) &&
                      ((size_t)NB * BN >= (size_t)N) && ((long)E <= (long)N * 33) &&
                      (nb1 >= NB);

    if (fits) {
        int2* pairs = (int2*)(base + oPairs);
        int*  cnt   = (int*)(base + oCnt);

        k1<<<nb1, 256, 0, stream>>>(x, W_rel, b_rel, W_root, y16, out, cnt, NB, N);
        scatterB<<<(E + EPB - 1) / EPB, TPS, 0, stream>>>(ei, ew, cnt, pairs, E);
        aggregateS16<<<NB, 512, 0, stream>>>(pairs, cnt, y16, out, N);
    } else {
        k1<<<nb1, 256, 0, stream>>>(x, W_rel, b_rel, W_root, y16, out,
                                    (int*)nullptr, 0, N);
        const long thr2 = (long)E * 16;
        k2_atomic16<<<(int)((thr2 + 255) / 256), 256, 0, stream>>>(ei, ew, y16, out, E);
    }
}

// Round 8
// 249.696 us; speedup vs baseline: 6.2838x; 1.0699x over previous
//
#include <hip/hip_runtime.h>

#define IN_CH 65
#define HID 64
#define BN 64        // nodes per bucket
#define NB 1563      // ceil(100000 / BN)
#define CAP 2560     // pair slots per bucket (mean 2048, +11 sigma)
#define SCAP 2432    // LDS sorted capacity (mean 2048, +8.5 sigma)
#define EPB 8192     // edges per scatter block
#define TPS 1024     // scatter threads per block
#define EPT (EPB / TPS)  // 8 edges per thread
#define WSTR 132     // k1 LDS W row stride (mult of 4: keeps b128 alignment)

static inline size_t align16(size_t v) { return (v + 15) & ~(size_t)15; }

__device__ inline ushort f2bf(float f) {
    uint u = __float_as_uint(f);
    return (ushort)((u + 0x7FFF + ((u >> 16) & 1)) >> 16);  // RNE
}
__device__ inline float bf2f(ushort h) { return __uint_as_float((uint)h << 16); }

// ---------------------------------------------------------------------------
// k1: per 64-node tile: y16 = bf16(x @ W_rel.T), out = x @ W_root.T + b_rel.
// W staging iterates the SOURCE flat index: coalesced global dword reads,
// transposed LDS writes (stride 132 -> <=8-way write conflict, once/block).
// Zeroes cnt (grid >= NB).
// ---------------------------------------------------------------------------
__global__ __launch_bounds__(256) void k1(const float* __restrict__ x,
                                          const float* __restrict__ W_rel,
                                          const float* __restrict__ b_rel,
                                          const float* __restrict__ W_root,
                                          ushort* __restrict__ y16,
                                          float* __restrict__ out,
                                          int* __restrict__ cnt, int nBuckets,
                                          int nNodes) {
    __shared__ float xs[64 * IN_CH];     // 16.6 KB
    __shared__ float ws[IN_CH * WSTR];   // 34.3 KB
    const int tid = threadIdx.x;
    const int tx = tid & 15;
    const int ty = tid >> 4;
    const long nodeBase = (long)blockIdx.x * 64;
    const int nValid = min(64, nNodes - (int)nodeBase);
    const int nx = nValid * IN_CH;

    if (cnt && tid == 0 && blockIdx.x < (unsigned)nBuckets) cnt[blockIdx.x] = 0;

    // coalesced read of W_rel/W_root, transposed write into ws:
    // ws[c*WSTR + j]      = W_rel[j][c]   (j in [0,64))
    // ws[c*WSTR + 64 + j] = W_root[j][c]
    for (int f = tid; f < HID * IN_CH; f += 256) {
        const int j = f / IN_CH, c = f - j * IN_CH;
        ws[c * WSTR + j] = W_rel[f];
    }
    for (int f = tid; f < HID * IN_CH; f += 256) {
        const int j = f / IN_CH, c = f - j * IN_CH;
        ws[c * WSTR + HID + j] = W_root[f];
    }
    const float* xsrc = x + nodeBase * IN_CH;
    for (int i = tid; i < 64 * IN_CH; i += 256) xs[i] = (i < nx) ? xsrc[i] : 0.f;
    __syncthreads();

    float acc[4][8];
#pragma unroll
    for (int i = 0; i < 4; ++i)
#pragma unroll
        for (int j = 0; j < 8; ++j) acc[i][j] = 0.f;

    const int r0 = ty * 4;
    const int c0 = tx * 8;
    for (int k = 0; k < IN_CH; ++k) {
        float aa[4] = {xs[(r0 + 0) * IN_CH + k], xs[(r0 + 1) * IN_CH + k],
                       xs[(r0 + 2) * IN_CH + k], xs[(r0 + 3) * IN_CH + k]};
        float4 b0 = *(const float4*)&ws[k * WSTR + c0];
        float4 b1 = *(const float4*)&ws[k * WSTR + c0 + 4];
        float bb[8] = {b0.x, b0.y, b0.z, b0.w, b1.x, b1.y, b1.z, b1.w};
#pragma unroll
        for (int i = 0; i < 4; ++i)
#pragma unroll
            for (int j = 0; j < 8; ++j) acc[i][j] += aa[i] * bb[j];
    }

    if (c0 >= HID) {
        const int h0 = c0 - HID;
        float4 bb0 = *(const float4*)&b_rel[h0];
        float4 bb1 = *(const float4*)&b_rel[h0 + 4];
        float bv[8] = {bb0.x, bb0.y, bb0.z, bb0.w, bb1.x, bb1.y, bb1.z, bb1.w};
#pragma unroll
        for (int i = 0; i < 4; ++i)
#pragma unroll
            for (int j = 0; j < 8; ++j) acc[i][j] += bv[j];
    }

#pragma unroll
    for (int i = 0; i < 4; ++i) {
        const long node = nodeBase + r0 + i;
        if (node >= nNodes) break;
        if (c0 < HID) {
            uint4 pk;
            pk.x = (uint)f2bf(acc[i][0]) | ((uint)f2bf(acc[i][1]) << 16);
            pk.y = (uint)f2bf(acc[i][2]) | ((uint)f2bf(acc[i][3]) << 16);
            pk.z = (uint)f2bf(acc[i][4]) | ((uint)f2bf(acc[i][5]) << 16);
            pk.w = (uint)f2bf(acc[i][6]) | ((uint)f2bf(acc[i][7]) << 16);
            *(uint4*)&y16[node * HID + c0] = pk;
        } else {
            float* dst = out + node * HID + (c0 - HID);
            *(float4*)(dst + 0) = make_float4(acc[i][0], acc[i][1], acc[i][2], acc[i][3]);
            *(float4*)(dst + 4) = make_float4(acc[i][4], acc[i][5], acc[i][6], acc[i][7]);
        }
    }
}

// ---------------------------------------------------------------------------
// scatterB: 1024-thread blocks, 8 edges/thread register-cached (constant-
// indexed after unroll). pair.x = (src<<7) | (dstLocal<<25): the masked value
// IS the byte offset of y16's row (src*128) — aggregate does no multiply.
// ---------------------------------------------------------------------------
__global__ __launch_bounds__(TPS) void scatterB(const int* __restrict__ ei,
                                                const float* __restrict__ ew,
                                                int* __restrict__ cnt,
                                                int2* __restrict__ pairs, int E) {
    __shared__ int lhist[NB];  // 6.2 KB
    __shared__ int lbase[NB];  // 6.2 KB
    const int tid = threadIdx.x;
    const long e0 = (long)blockIdx.x * EPB;
    const int n = (int)min((long)EPB, (long)E - e0);

    for (int i = tid; i < NB; i += TPS) lhist[i] = 0;
    __syncthreads();

    int dstv[EPT], srcv[EPT];
    float wv[EPT];
#pragma unroll
    for (int k = 0; k < EPT; ++k) {
        const int i = tid + k * TPS;
        const bool valid = i < n;
        dstv[k] = valid ? ei[(long)E + e0 + i] : 0;
        srcv[k] = valid ? ei[e0 + i] : 0;
        wv[k]   = valid ? ew[e0 + i] : 0.f;
        if (valid) atomicAdd(&lhist[dstv[k] >> 6], 1);
    }
    __syncthreads();

    for (int i = tid; i < NB; i += TPS) {
        const int c = lhist[i];
        lbase[i] = c ? atomicAdd(&cnt[i], c) : 0;
        lhist[i] = 0;  // reuse as local cursor
    }
    __syncthreads();

#pragma unroll
    for (int k = 0; k < EPT; ++k) {
        const int i = tid + k * TPS;
        if (i < n) {
            const int b = dstv[k] >> 6;
            const int p = lbase[b] + atomicAdd(&lhist[b], 1);
            if (p < CAP)
                pairs[(size_t)b * CAP + p] =
                    make_int2((srcv[k] << 7) | ((dstv[k] & (BN - 1)) << 25),
                              __float_as_int(wv[k]));
        }
    }
}

// ---------------------------------------------------------------------------
// aggregateS16: one 512-thread block per 64-node bucket.
// Phase A: LDS counting sort into per-node segments (int atomics only);
//          sorted[].x holds the y16 row BYTE OFFSET (src*128).
// Phase B: half-wave channel pairing — half h of each wave processes edge
//          k+h; each lane loads a uint (2 bf16 channels) at srcOff+lane4.
//          Per 2 edges: 1 dword gather + ~7 VALU. Halves merged once per
//          node via __shfl_xor(.,32); half 0 does the float2 out +=.
// ---------------------------------------------------------------------------
__global__ __launch_bounds__(512) void aggregateS16(const int2* __restrict__ pairs,
                                                    const int* __restrict__ cnt,
                                                    const ushort* __restrict__ y16,
                                                    float* __restrict__ out, int N) {
    __shared__ int2 sorted[SCAP];  // 19.5 KB
    __shared__ int sH[BN];
    __shared__ int soff[BN + 1];
    __shared__ int scur[BN];
    const int tid = threadIdx.x;
    const int lane = tid & 63;
    const int wv = tid >> 6;       // 0..7
    const int half = lane >> 5;    // 0/1: which edge of the pair
    const uint lane4 = (lane & 31) * 4;  // byte offset of this lane's 2 channels
    const int b = blockIdx.x;

    if (tid < BN) { sH[tid] = 0; scur[tid] = 0; }
    __syncthreads();

    const int m = min(cnt[b], CAP);
    const int2* pb = pairs + (size_t)b * CAP;

    for (int i = tid; i < m; i += 512)
        atomicAdd(&sH[(uint)pb[i].x >> 25], 1);
    __syncthreads();

    for (int off = 1; off < BN; off <<= 1) {
        int v = 0;
        if (tid < BN) {
            v = sH[tid];
            if (tid >= off) v += sH[tid - off];
        }
        __syncthreads();
        if (tid < BN) sH[tid] = v;
        __syncthreads();
    }
    if (tid < BN) soff[tid + 1] = sH[tid];
    if (tid == 0) soff[0] = 0;
    __syncthreads();

    for (int i = tid; i < m; i += 512) {
        const int2 p = pb[i];
        const int d = (uint)p.x >> 25;
        const int slot = soff[d] + atomicAdd(&scur[d], 1);
        if (slot < SCAP) sorted[slot] = make_int2(p.x & 0x00FFFF80, p.y);
    }
    __syncthreads();

    const char* yb = (const char*)y16;
    const long nodeBase = (long)b * BN;
    for (int nl = wv; nl < BN; nl += 8) {
        const long node = nodeBase + nl;
        if (node >= N) break;
        const int kbeg = min(soff[nl], SCAP);
        const int kend = min(soff[nl + 1], SCAP);
        float ax = 0.f, ay = 0.f;
        int k = kbeg + half;
        for (; k + 6 < kend; k += 8) {
            const int2 p0 = sorted[k],     p1 = sorted[k + 2];
            const int2 p2 = sorted[k + 4], p3 = sorted[k + 6];
            const uint q0 = *(const uint*)(yb + (uint)p0.x + lane4);
            const uint q1 = *(const uint*)(yb + (uint)p1.x + lane4);
            const uint q2 = *(const uint*)(yb + (uint)p2.x + lane4);
            const uint q3 = *(const uint*)(yb + (uint)p3.x + lane4);
            const float w0 = __int_as_float(p0.y), w1 = __int_as_float(p1.y);
            const float w2 = __int_as_float(p2.y), w3 = __int_as_float(p3.y);
            ax += w0 * __uint_as_float(q0 << 16);
            ay += w0 * __uint_as_float(q0 & 0xFFFF0000u);
            ax += w1 * __uint_as_float(q1 << 16);
            ay += w1 * __uint_as_float(q1 & 0xFFFF0000u);
            ax += w2 * __uint_as_float(q2 << 16);
            ay += w2 * __uint_as_float(q2 & 0xFFFF0000u);
            ax += w3 * __uint_as_float(q3 << 16);
            ay += w3 * __uint_as_float(q3 & 0xFFFF0000u);
        }
        for (; k < kend; k += 2) {
            const int2 p = sorted[k];
            const uint q = *(const uint*)(yb + (uint)p.x + lane4);
            const float w = __int_as_float(p.y);
            ax += w * __uint_as_float(q << 16);
            ay += w * __uint_as_float(q & 0xFFFF0000u);
        }
        // merge the two halves (lane ^ 32 holds the other edge-parity sum)
        ax += __shfl_xor(ax, 32);
        ay += __shfl_xor(ay, 32);
        if (half == 0) {
            float2* o = (float2*)(out + node * HID) + (lane & 31);
            const float2 cur = *o;
            *o = make_float2(cur.x + ax, cur.y + ay);
        }
    }
}

// Fallback: 16 thr/edge atomic scatter from bf16 y.
__global__ __launch_bounds__(256) void k2_atomic16(const int* __restrict__ ei,
                                                   const float* __restrict__ ew,
                                                   const ushort* __restrict__ y16,
                                                   float* __restrict__ out, int E) {
    const long t = (long)blockIdx.x * 256 + threadIdx.x;
    const long e = t >> 4;
    const int r = (int)(t & 15);
    if (e >= E) return;
    const int src = ei[e];
    const int dst = ei[(long)E + e];
    const float w = ew[e];
    const uint2 q = ((const uint2*)y16)[(size_t)src * 16 + r];
    float* o = out + (size_t)dst * HID + r * 4;
    unsafeAtomicAdd(o + 0, w * __uint_as_float(q.x << 16));
    unsafeAtomicAdd(o + 1, w * __uint_as_float(q.x & 0xFFFF0000u));
    unsafeAtomicAdd(o + 2, w * __uint_as_float(q.y << 16));
    unsafeAtomicAdd(o + 3, w * __uint_as_float(q.y & 0xFFFF0000u));
}

extern "C" void kernel_launch(void* const* d_in, const int* in_sizes, int n_in,
                              void* d_out, int out_size, void* d_ws, size_t ws_size,
                              hipStream_t stream) {
    const float* x      = (const float*)d_in[0];
    const int*   ei     = (const int*)d_in[1];
    const float* ew     = (const float*)d_in[2];
    const float* W_rel  = (const float*)d_in[3];
    const float* b_rel  = (const float*)d_in[4];
    const float* W_root = (const float*)d_in[5];
    float* out = (float*)d_out;

    const int N = in_sizes[0] / IN_CH;  // 100000
    const int E = in_sizes[2];          // 3200000

    // ws layout: y16 | pairs | cnt
    char* base = (char*)d_ws;
    const size_t oY     = 0;
    const size_t oPairs = align16((size_t)N * HID * 2);
    const size_t oCnt   = oPairs + align16((size_t)NB * CAP * 8);
    const size_t need   = oCnt + (size_t)NB * 4;

    ushort* y16 = (ushort*)(base + oY);
    const int nb1 = (N + 63) / 64;

    const bool fits = (ws_size >= need) && (N <= (1 << 17)) &&
                      ((size_t)NB * BN >= (size_t)N) && ((long)E <= (long)N * 33) &&
                      (nb1 >= NB);

    if (fits) {
        int2* pairs = (int2*)(base + oPairs);
        int*  cnt   = (int*)(base + oCnt);

        k1<<<nb1, 256, 0, stream>>>(x, W_rel, b_rel, W_root, y16, out, cnt, NB, N);
        scatterB<<<(E + EPB - 1) / EPB, TPS, 0, stream>>>(ei, ew, cnt, pairs, E);
        aggregateS16<<<NB, 512, 0, stream>>>(pairs, cnt, y16, out, N);
    } else {
        k1<<<nb1, 256, 0, stream>>>(x, W_rel, b_rel, W_root, y16, out,
                                    (int*)nullptr, 0, N);
        const long thr2 = (long)E * 16;
        k2_atomic16<<<(int)((thr2 + 255) / 256), 256, 0, stream>>>(ei, ew, y16, out, E);
    }
}